// Round 4
// baseline (775.582 us; speedup 1.0000x reference)
//
#include <hip/hip_runtime.h>

typedef unsigned short u16;
using short8 = __attribute__((ext_vector_type(8))) short;
using f32x4  = __attribute__((ext_vector_type(4))) float;
using u16x4  = __attribute__((ext_vector_type(4))) unsigned short;

__device__ __forceinline__ u16 f2bf(float f) {
  union { float f; unsigned int u; } v; v.f = f;
  unsigned int u = v.u + 0x7FFFu + ((v.u >> 16) & 1u);
  return (u16)(u >> 16);
}
__device__ __forceinline__ float bf2f(u16 u) {
  union { unsigned int u; float f; } v; v.u = ((unsigned int)u) << 16;
  return v.f;
}
// async global->LDS, 16B per lane. LDS dest = wave-uniform base + lane*16.
__device__ __forceinline__ void glds16(const void* g, void* l) {
  __builtin_amdgcn_global_load_lds(
      (const __attribute__((address_space(1))) void*)g,
      (__attribute__((address_space(3))) void*)l, 16, 0, 0);
}

// ---------------- merged f32 -> bf16 casts ----------------
__global__ __launch_bounds__(256) void cast_all(
    const float* __restrict__ x, const float* __restrict__ wq,
    const float* __restrict__ wk, const float* __restrict__ wv,
    const float* __restrict__ wo,
    u16* __restrict__ xb, u16* __restrict__ wqb, u16* __restrict__ wkb,
    u16* __restrict__ wvb, u16* __restrict__ wob) {
  int i = blockIdx.x * 256 + threadIdx.x;
  const float4* src; ushort4* dst; int off;
  if (i < 1048576)      { src = (const float4*)x;  dst = (ushort4*)xb;  off = i; }
  else if (i < 1310720) { src = (const float4*)wq; dst = (ushort4*)wqb; off = i - 1048576; }
  else if (i < 1572864) { src = (const float4*)wk; dst = (ushort4*)wkb; off = i - 1310720; }
  else if (i < 1835008) { src = (const float4*)wv; dst = (ushort4*)wvb; off = i - 1572864; }
  else                  { src = (const float4*)wo; dst = (ushort4*)wob; off = i - 1835008; }
  float4 v = src[off];
  ushort4 o;
  o.x = f2bf(v.x); o.y = f2bf(v.y); o.z = f2bf(v.z); o.w = f2bf(v.w);
  dst[off] = o;
}

// ---------------- NT GEMM with global_load_lds staging ----------------
// MODE 0: fused QKV. sel0 -> Q bf16 scaled by 0.125 (exact pow2, folded attn scale);
//         sel1 -> K bf16; sel2 -> V written TRANSPOSED bf16 into (B,1024,2048).
// MODE 1: fp32 out (output projection).
template<int MODE>
__global__ __launch_bounds__(256) void gemm_nt_glds(
    const u16* __restrict__ A,
    const u16* __restrict__ B0, const u16* __restrict__ B1, const u16* __restrict__ B2,
    const float* __restrict__ bias0, const float* __restrict__ bias1, const float* __restrict__ bias2,
    void* __restrict__ C0, void* __restrict__ C1, void* __restrict__ C2,
    int K)
{
  // As = smem[0:8192) u16, Bs = smem[8192:16384); full array doubles as 128x132
  // transpose scratch for the sel==2 epilogue (pad 132 -> conflict-free, 8B aligned).
  __shared__ u16 smem[16896];
  u16* As = smem;
  u16* Bs = smem + 8192;
  const int bn = blockIdx.x, bm = blockIdx.y;
  const int sel = bn >> 3, bnl = bn & 7;
  const u16* B = sel == 0 ? B0 : (sel == 1 ? B1 : B2);
  const float* bias = sel == 0 ? bias0 : (sel == 1 ? bias1 : bias2);
  void* C = sel == 0 ? C0 : (sel == 1 ? C1 : C2);

  const int tid = threadIdx.x;
  const int w = tid >> 6, lane = tid & 63, quad = lane >> 4, l16 = lane & 15;
  const int wm = w >> 1, wn = w & 1;
  const int srow = lane >> 3, gc = (lane & 7) ^ srow;

  const u16* aseg = A + (size_t)(bm * 128 + w * 32 + srow) * K + gc * 8;
  const u16* bseg = B + (size_t)(bnl * 128 + w * 32 + srow) * K + gc * 8;

  const f32x4 z4 = {0.f, 0.f, 0.f, 0.f};
  f32x4 acc[4][4];
#pragma unroll
  for (int mt = 0; mt < 4; mt++)
#pragma unroll
    for (int nt = 0; nt < 4; nt++) acc[mt][nt] = z4;

  for (int k0 = 0; k0 < K; k0 += 64) {
    __syncthreads();
#pragma unroll
    for (int j = 0; j < 4; j++) {
      glds16(aseg + (size_t)(j * 8) * K + k0, As + (w * 4 + j) * 512);
      glds16(bseg + (size_t)(j * 8) * K + k0, Bs + (w * 4 + j) * 512);
    }
    __syncthreads();
#pragma unroll
    for (int ks = 0; ks < 2; ks++) {
      short8 af[4], bf[4];
#pragma unroll
      for (int mt = 0; mt < 4; mt++) {
        int row = wm * 64 + mt * 16 + l16;
        int chk = (ks * 4 + quad) ^ (row & 7);
        af[mt] = *(const short8*)((const short*)As + row * 64 + chk * 8);
      }
#pragma unroll
      for (int nt = 0; nt < 4; nt++) {
        int row = wn * 64 + nt * 16 + l16;
        int chk = (ks * 4 + quad) ^ (row & 7);
        bf[nt] = *(const short8*)((const short*)Bs + row * 64 + chk * 8);
      }
#pragma unroll
      for (int mt = 0; mt < 4; mt++)
#pragma unroll
        for (int nt = 0; nt < 4; nt++)
          acc[mt][nt] = __builtin_amdgcn_mfma_f32_16x16x32_bf16(af[mt], bf[nt], acc[mt][nt], 0, 0, 0);
    }
  }

  if (MODE == 0 && sel == 2) {
    // V: transpose through LDS, write bf16 (B,1024,2048) directly.
    __syncthreads();  // all K-loop LDS reads finished before overwrite
#pragma unroll
    for (int mt = 0; mt < 4; mt++) {
      int r0 = wm * 64 + mt * 16 + quad * 4;
#pragma unroll
      for (int nt = 0; nt < 4; nt++) {
        int c = wn * 64 + nt * 16 + l16;
        float bvv = bias[bnl * 128 + c];
        u16x4 pk;
#pragma unroll
        for (int r = 0; r < 4; r++) pk[r] = f2bf(acc[mt][nt][r] + bvv);
        *(u16x4*)(smem + c * 132 + r0) = pk;
      }
    }
    __syncthreads();
    const int bb = bm >> 4;
    const size_t sb = (size_t)(bm & 15) * 128;
    u16* Cv = (u16*)C;
#pragma unroll
    for (int i = 0; i < 16; i++) {
      int idx = tid + i * 256;
      int dr = idx >> 5, c4 = (idx & 31) * 4;
      u16x4 v = *(const u16x4*)(smem + dr * 132 + c4);
      *(u16x4*)(Cv + ((size_t)bb * 1024 + bnl * 128 + dr) * 2048 + sb + c4) = v;
    }
  } else {
    const float cmul = (MODE == 0 && sel == 0) ? 0.125f : 1.0f;
#pragma unroll
    for (int mt = 0; mt < 4; mt++) {
      int row0 = bm * 128 + wm * 64 + mt * 16 + quad * 4;
#pragma unroll
      for (int nt = 0; nt < 4; nt++) {
        int col = bnl * 128 + wn * 64 + nt * 16 + l16;
        float bv = bias[col];
#pragma unroll
        for (int r = 0; r < 4; r++) {
          float v = (acc[mt][nt][r] + bv) * cmul;
          if (MODE) ((float*)C)[(size_t)(row0 + r) * 1024 + col] = v;
          else      ((u16*)C)[(size_t)(row0 + r) * 1024 + col] = f2bf(v);
        }
      }
    }
  }
}

// ---------------- fused causal attention ----------------
// v3: 512 threads (8 waves -> 4 waves/SIMD at 2 blocks/CU) + XCD-locality
// block remap (each XCD owns 4 (b,h) groups; K+V working set 2MB fits L2).
// Q in regs, K double-buffered w/ prefetch, hoisted rowsum reduce,
// diag-only masking, setprio on MFMA.
__global__ __launch_bounds__(512, 4) void attn_kernel(
    const u16* __restrict__ Qb, const u16* __restrict__ Kbuf,
    const u16* __restrict__ Vtb, float* __restrict__ attn,
    u16* __restrict__ ctx)
{
  __shared__ u16 Ks[2][128 * 64];  // sweep1: K dbuf; sweep2: [0]=K, [1]=Vt
  __shared__ u16 Ps[128 * 128];    // Q stage (pre-sweep) / P tile (sweep2)
  __shared__ float ls[128];

  // XCD-locality remap: xcd = flat&7 (HW round-robin), slot = flat>>3.
  // Each XCD gets bh in {4x..4x+3}; slots s and s+32 land on the same CU
  // with qb summing to 15 (load balance).
  const int flat = blockIdx.x;
  const int x = flat & 7, slot = flat >> 3;
  int bh, qb;
  if (slot < 32) { bh = x * 4 + (slot >> 4);            qb = slot & 15; }
  else           { bh = x * 4 + 2 + ((slot - 32) >> 4); qb = 15 - ((slot - 32) & 15); }
  const int b = bh >> 4, h = bh & 15;

  const int tid = threadIdx.x;
  const int w = tid >> 6, lane = tid & 63, quad = lane >> 4, l16 = lane & 15;
  const int wm = w >> 1, wn = w & 1;     // wm 0..3 (32 rows), wn 0..1 (64 cols)
  const int srow8 = lane >> 3, gc8 = (lane & 7) ^ srow8;
  const int srow16 = lane >> 4, sc16 = lane & 15;

  const int S = 2048, D = 1024;
  const u16* Qg = Qb + ((size_t)b * S + qb * 128) * D + h * 64;
  const u16* Kg = Kbuf + (size_t)b * S * D + h * 64;
  const u16* Vg = Vtb + ((size_t)b * D + h * 64) * S;
  float* attng = attn + ((size_t)(b * 16 + h) * S + qb * 128) * S;

  const f32x4 z4 = {0.f, 0.f, 0.f, 0.f};

  // stage Q -> Ps[0:8192) and K(0) -> Ks[0]; one barrier drains both
#pragma unroll
  for (int j = 0; j < 2; j++)
    glds16(Qg + (size_t)(w * 16 + j * 8 + srow8) * D + gc8 * 8, (u16*)Ps + (w * 2 + j) * 512);
  if (tid < 128) ls[tid] = 0.f;
#pragma unroll
  for (int j = 0; j < 2; j++)
    glds16(Kg + (size_t)(w * 16 + j * 8 + srow8) * D + gc8 * 8, Ks[0] + (w * 2 + j) * 512);
  __syncthreads();

  // Q fragments -> registers (invariant across kb loop)
  short8 qf[2][2];
#pragma unroll
  for (int mt = 0; mt < 2; mt++) {
    int row = wm * 32 + mt * 16 + l16;
#pragma unroll
    for (int ks = 0; ks < 2; ks++) {
      int chk = (ks * 4 + quad) ^ (row & 7);
      qf[mt][ks] = *(const short8*)((const short*)Ps + row * 64 + chk * 8);
    }
  }

  // ---- sweep 1: row sums of exp ----
  float rowsum[2][4];
#pragma unroll
  for (int mt = 0; mt < 2; mt++)
#pragma unroll
    for (int rr = 0; rr < 4; rr++) rowsum[mt][rr] = 0.f;

  for (int kb = 0; kb <= qb; kb++) {
    if (kb) __syncthreads();  // K(kb) ready (pre-loop barrier covers kb==0)
    if (kb < qb) {            // prefetch next tile; drained at NEXT top barrier
#pragma unroll
      for (int j = 0; j < 2; j++)
        glds16(Kg + (size_t)((kb + 1) * 128 + w * 16 + j * 8 + srow8) * D + gc8 * 8,
               Ks[(kb + 1) & 1] + (w * 2 + j) * 512);
    }
    const u16* kbf = Ks[kb & 1];
    f32x4 acc[2][4];
#pragma unroll
    for (int mt = 0; mt < 2; mt++)
#pragma unroll
      for (int nt = 0; nt < 4; nt++) acc[mt][nt] = z4;
    __builtin_amdgcn_s_setprio(1);
#pragma unroll
    for (int ks = 0; ks < 2; ks++) {
      short8 bf[4];
#pragma unroll
      for (int nt = 0; nt < 4; nt++) {
        int row = wn * 64 + nt * 16 + l16;
        int chk = (ks * 4 + quad) ^ (row & 7);
        bf[nt] = *(const short8*)((const short*)kbf + row * 64 + chk * 8);
      }
#pragma unroll
      for (int mt = 0; mt < 2; mt++)
#pragma unroll
        for (int nt = 0; nt < 4; nt++)
          acc[mt][nt] = __builtin_amdgcn_mfma_f32_16x16x32_bf16(qf[mt][ks], bf[nt], acc[mt][nt], 0, 0, 0);
    }
    __builtin_amdgcn_s_setprio(0);
    if (kb < qb) {  // full tile: no mask
#pragma unroll
      for (int mt = 0; mt < 2; mt++)
#pragma unroll
        for (int rr = 0; rr < 4; rr++) {
          float s = 0.f;
#pragma unroll
          for (int nt = 0; nt < 4; nt++)
            s += __expf(fminf(acc[mt][nt][rr], 30.f));
          rowsum[mt][rr] += s;
        }
    } else {        // diagonal tile: mask k>q
#pragma unroll
      for (int mt = 0; mt < 2; mt++)
#pragma unroll
        for (int rr = 0; rr < 4; rr++) {
          int rloc = wm * 32 + mt * 16 + quad * 4 + rr;
          float s = 0.f;
#pragma unroll
          for (int nt = 0; nt < 4; nt++) {
            int ck = wn * 64 + nt * 16 + l16;
            s += (ck <= rloc) ? __expf(fminf(acc[mt][nt][rr], 30.f)) : 0.f;
          }
          rowsum[mt][rr] += s;
        }
    }
  }

  // one reduction for the whole sweep
#pragma unroll
  for (int mt = 0; mt < 2; mt++)
#pragma unroll
    for (int rr = 0; rr < 4; rr++) {
      float s = rowsum[mt][rr];
      s += __shfl_xor(s, 1);
      s += __shfl_xor(s, 2);
      s += __shfl_xor(s, 4);
      s += __shfl_xor(s, 8);
      if (l16 == 0) atomicAdd(&ls[wm * 32 + mt * 16 + quad * 4 + rr], s);
    }
  __syncthreads();
  float rl[2][4];
#pragma unroll
  for (int mt = 0; mt < 2; mt++)
#pragma unroll
    for (int rr = 0; rr < 4; rr++)
      rl[mt][rr] = 1.0f / ls[wm * 32 + mt * 16 + quad * 4 + rr];

  // restage K(0) for sweep 2 (drained at first top barrier)
#pragma unroll
  for (int j = 0; j < 2; j++)
    glds16(Kg + (size_t)(w * 16 + j * 8 + srow8) * D + gc8 * 8, Ks[0] + (w * 2 + j) * 512);

  f32x4 cacc[4];
#pragma unroll
  for (int nt = 0; nt < 4; nt++) cacc[nt] = z4;

  // ---- sweep 2: attn values + PV ----
  for (int kb = 0; kb <= qb; kb++) {
    __syncthreads();  // K(kb) ready; prev PV reads + prev attn stores done
    // stage Vt(kb) -> Ks[1]; drained at mid barrier (covered by QK+exp)
#pragma unroll
    for (int j = 0; j < 2; j++) {
      int r0v = (w * 2 + j) * 4;
      int row = r0v + srow16;
      int gcv = sc16 ^ (row & 7);
      glds16(Vg + (size_t)row * S + kb * 128 + gcv * 8, Ks[1] + r0v * 128);
    }
    f32x4 acc[2][4];
#pragma unroll
    for (int mt = 0; mt < 2; mt++)
#pragma unroll
      for (int nt = 0; nt < 4; nt++) acc[mt][nt] = z4;
    __builtin_amdgcn_s_setprio(1);
#pragma unroll
    for (int ks = 0; ks < 2; ks++) {
      short8 bf[4];
#pragma unroll
      for (int nt = 0; nt < 4; nt++) {
        int row = wn * 64 + nt * 16 + l16;
        int chk = (ks * 4 + quad) ^ (row & 7);
        bf[nt] = *(const short8*)((const short*)Ks[0] + row * 64 + chk * 8);
      }
#pragma unroll
      for (int mt = 0; mt < 2; mt++)
#pragma unroll
        for (int nt = 0; nt < 4; nt++)
          acc[mt][nt] = __builtin_amdgcn_mfma_f32_16x16x32_bf16(qf[mt][ks], bf[nt], acc[mt][nt], 0, 0, 0);
    }
    __builtin_amdgcn_s_setprio(0);
    // epilogue: P -> Ps (bf16, XOR-swizzled rows), normalized
    bool diag = (kb == qb);
#pragma unroll
    for (int mt = 0; mt < 2; mt++)
#pragma unroll
      for (int rr = 0; rr < 4; rr++) {
        int rloc = wm * 32 + mt * 16 + quad * 4 + rr;
        float rlv = rl[mt][rr];
#pragma unroll
        for (int nt = 0; nt < 4; nt++) {
          int colk = wn * 64 + nt * 16 + l16;
          float e = __expf(fminf(acc[mt][nt][rr], 30.f)) * rlv;
          if (diag && colk > rloc) e = 0.f;
          Ps[rloc * 128 + (((colk >> 3) ^ (rloc & 7)) << 3) + (colk & 7)] = f2bf(e);
        }
      }
    __syncthreads();  // Ps ready + Vt drained
    // restage K(kb+1) (QK reads of Ks[0] all done); drained at next top barrier
    if (kb < qb) {
#pragma unroll
      for (int j = 0; j < 2; j++)
        glds16(Kg + (size_t)((kb + 1) * 128 + w * 16 + j * 8 + srow8) * D + gc8 * 8,
               Ks[0] + (w * 2 + j) * 512);
    }
    // attn write from Ps: coalesced NT dwordx4 (overlaps K prefetch latency)
#pragma unroll
    for (int s = 0; s < 8; s++) {
      int e4 = s * 512 + tid;
      int row = e4 >> 5, col = (e4 & 31) * 4;
      int chunk = (col >> 3) ^ (row & 7);
      u16x4 pv = *(const u16x4*)((const u16*)Ps + row * 128 + chunk * 8 + (col & 7));
      f32x4 o;
      o[0] = bf2f(pv[0]); o[1] = bf2f(pv[1]); o[2] = bf2f(pv[2]); o[3] = bf2f(pv[3]);
      __builtin_nontemporal_store(o, (f32x4*)(attng + (size_t)row * S + kb * 128 + col));
    }
    // PV: each wave 16 rows x 64 cols
    __builtin_amdgcn_s_setprio(1);
#pragma unroll
    for (int ks = 0; ks < 4; ks++) {
      short8 pf, vf[4];
      {
        int row = w * 16 + l16;
        int chk = (ks * 4 + quad) ^ (row & 7);
        pf = *(const short8*)((const short*)Ps + row * 128 + chk * 8);
      }
#pragma unroll
      for (int nt = 0; nt < 4; nt++) {
        int row = nt * 16 + l16;
        int chk = (ks * 4 + quad) ^ (row & 7);
        vf[nt] = *(const short8*)((const short*)Ks[1] + row * 128 + chk * 8);
      }
#pragma unroll
      for (int nt = 0; nt < 4; nt++)
        cacc[nt] = __builtin_amdgcn_mfma_f32_16x16x32_bf16(pf, vf[nt], cacc[nt], 0, 0, 0);
    }
    __builtin_amdgcn_s_setprio(0);
  }

  // zero-fill strictly-upper k-blocks of attn (NT)
  {
    int kstart = (qb + 1) * 128;
    const f32x4 zz = {0.f, 0.f, 0.f, 0.f};
    for (int rr = 0; rr < 128; rr++) {
      float* rowp = attng + (size_t)rr * S;
      for (int c = kstart + tid * 4; c < S; c += 2048)
        __builtin_nontemporal_store(zz, (f32x4*)(rowp + c));
    }
  }

  // ctx write (bf16, (B,S,D) layout)
#pragma unroll
  for (int nt = 0; nt < 4; nt++)
#pragma unroll
    for (int rr = 0; rr < 4; rr++) {
      int row_local = w * 16 + quad * 4 + rr;
      int col = nt * 16 + l16;
      ctx[((size_t)b * S + qb * 128 + row_local) * D + h * 64 + col] = f2bf(cacc[nt][rr]);
    }
}

extern "C" void kernel_launch(void* const* d_in, const int* in_sizes, int n_in,
                              void* d_out, int out_size, void* d_ws, size_t ws_size,
                              hipStream_t stream) {
  const float* x  = (const float*)d_in[0];
  const float* Wq = (const float*)d_in[1];
  const float* bq = (const float*)d_in[2];
  const float* Wk = (const float*)d_in[3];
  const float* bk = (const float*)d_in[4];
  const float* Wv = (const float*)d_in[5];
  const float* bv = (const float*)d_in[6];
  const float* Wo = (const float*)d_in[7];
  const float* bo = (const float*)d_in[8];

  float* out_f32  = (float*)d_out;              // (B,S,D) fp32
  float* attn_out = (float*)d_out + 4194304;    // (B,H,S,S) fp32

  char* w = (char*)d_ws;
  u16* xb   = (u16*)(w + 0);
  u16* Wqb  = (u16*)(w + 8388608);
  u16* Wkb  = (u16*)(w + 10485760);
  u16* Wvb  = (u16*)(w + 12582912);
  u16* Wob  = (u16*)(w + 14680064);
  u16* Qbuf = (u16*)(w + 16777216);
  u16* Kbuf = (u16*)(w + 25165824);
  u16* Vtb  = (u16*)(w + 41943040);
  u16* ctxb = (u16*)(w + 50331648);

  cast_all<<<8192, 256, 0, stream>>>(x, Wq, Wk, Wv, Wo, xb, Wqb, Wkb, Wvb, Wob);

  // fused QKV projection; Q pre-scaled by 0.125; V written transposed
  gemm_nt_glds<0><<<dim3(24, 32), 256, 0, stream>>>(
      xb, Wqb, Wkb, Wvb, bq, bk, bv, Qbuf, Kbuf, Vtb, 1024);

  attn_kernel<<<512, 512, 0, stream>>>(Qbuf, Kbuf, Vtb, attn_out, ctxb);

  gemm_nt_glds<1><<<dim3(8, 32), 256, 0, stream>>>(
      ctxb, Wob, Wob, Wob, bo, bo, bo, out_f32, out_f32, out_f32, 1024);
}

// Round 5
// 691.903 us; speedup vs baseline: 1.1209x; 1.1209x over previous
//
#include <hip/hip_runtime.h>

typedef unsigned short u16;
using short8 = __attribute__((ext_vector_type(8))) short;
using f32x4  = __attribute__((ext_vector_type(4))) float;
using u16x4  = __attribute__((ext_vector_type(4))) unsigned short;

__device__ __forceinline__ u16 f2bf(float f) {
  union { float f; unsigned int u; } v; v.f = f;
  unsigned int u = v.u + 0x7FFFu + ((v.u >> 16) & 1u);
  return (u16)(u >> 16);
}
__device__ __forceinline__ float bf2f(u16 u) {
  union { unsigned int u; float f; } v; v.u = ((unsigned int)u) << 16;
  return v.f;
}
// async global->LDS, 16B per lane. LDS dest = wave-uniform base + lane*16.
__device__ __forceinline__ void glds16(const void* g, void* l) {
  __builtin_amdgcn_global_load_lds(
      (const __attribute__((address_space(1))) void*)g,
      (__attribute__((address_space(3))) void*)l, 16, 0, 0);
}

// ---------------- merged f32 -> bf16 casts ----------------
__global__ __launch_bounds__(256) void cast_all(
    const float* __restrict__ x, const float* __restrict__ wq,
    const float* __restrict__ wk, const float* __restrict__ wv,
    const float* __restrict__ wo,
    u16* __restrict__ xb, u16* __restrict__ wqb, u16* __restrict__ wkb,
    u16* __restrict__ wvb, u16* __restrict__ wob) {
  int i = blockIdx.x * 256 + threadIdx.x;
  const float4* src; ushort4* dst; int off;
  if (i < 1048576)      { src = (const float4*)x;  dst = (ushort4*)xb;  off = i; }
  else if (i < 1310720) { src = (const float4*)wq; dst = (ushort4*)wqb; off = i - 1048576; }
  else if (i < 1572864) { src = (const float4*)wk; dst = (ushort4*)wkb; off = i - 1310720; }
  else if (i < 1835008) { src = (const float4*)wv; dst = (ushort4*)wvb; off = i - 1572864; }
  else                  { src = (const float4*)wo; dst = (ushort4*)wob; off = i - 1835008; }
  float4 v = src[off];
  ushort4 o;
  o.x = f2bf(v.x); o.y = f2bf(v.y); o.z = f2bf(v.z); o.w = f2bf(v.w);
  dst[off] = o;
}

// ---------------- NT GEMM with global_load_lds staging ----------------
// MODE 0: fused QKV. sel0 -> Q bf16 scaled by 0.125 (exact pow2, folded attn scale);
//         sel1 -> K bf16; sel2 -> V written TRANSPOSED bf16 into (B,1024,2048).
// MODE 1: fp32 out (output projection).
template<int MODE>
__global__ __launch_bounds__(256) void gemm_nt_glds(
    const u16* __restrict__ A,
    const u16* __restrict__ B0, const u16* __restrict__ B1, const u16* __restrict__ B2,
    const float* __restrict__ bias0, const float* __restrict__ bias1, const float* __restrict__ bias2,
    void* __restrict__ C0, void* __restrict__ C1, void* __restrict__ C2,
    int K)
{
  // As = smem[0:8192) u16, Bs = smem[8192:16384); full array doubles as 128x132
  // transpose scratch for the sel==2 epilogue (pad 132 -> conflict-free, 8B aligned).
  __shared__ u16 smem[16896];
  u16* As = smem;
  u16* Bs = smem + 8192;
  const int bn = blockIdx.x, bm = blockIdx.y;
  const int sel = bn >> 3, bnl = bn & 7;
  const u16* B = sel == 0 ? B0 : (sel == 1 ? B1 : B2);
  const float* bias = sel == 0 ? bias0 : (sel == 1 ? bias1 : bias2);
  void* C = sel == 0 ? C0 : (sel == 1 ? C1 : C2);

  const int tid = threadIdx.x;
  const int w = tid >> 6, lane = tid & 63, quad = lane >> 4, l16 = lane & 15;
  const int wm = w >> 1, wn = w & 1;
  const int srow = lane >> 3, gc = (lane & 7) ^ srow;

  const u16* aseg = A + (size_t)(bm * 128 + w * 32 + srow) * K + gc * 8;
  const u16* bseg = B + (size_t)(bnl * 128 + w * 32 + srow) * K + gc * 8;

  const f32x4 z4 = {0.f, 0.f, 0.f, 0.f};
  f32x4 acc[4][4];
#pragma unroll
  for (int mt = 0; mt < 4; mt++)
#pragma unroll
    for (int nt = 0; nt < 4; nt++) acc[mt][nt] = z4;

  for (int k0 = 0; k0 < K; k0 += 64) {
    __syncthreads();
#pragma unroll
    for (int j = 0; j < 4; j++) {
      glds16(aseg + (size_t)(j * 8) * K + k0, As + (w * 4 + j) * 512);
      glds16(bseg + (size_t)(j * 8) * K + k0, Bs + (w * 4 + j) * 512);
    }
    __syncthreads();
#pragma unroll
    for (int ks = 0; ks < 2; ks++) {
      short8 af[4], bf[4];
#pragma unroll
      for (int mt = 0; mt < 4; mt++) {
        int row = wm * 64 + mt * 16 + l16;
        int chk = (ks * 4 + quad) ^ (row & 7);
        af[mt] = *(const short8*)((const short*)As + row * 64 + chk * 8);
      }
#pragma unroll
      for (int nt = 0; nt < 4; nt++) {
        int row = wn * 64 + nt * 16 + l16;
        int chk = (ks * 4 + quad) ^ (row & 7);
        bf[nt] = *(const short8*)((const short*)Bs + row * 64 + chk * 8);
      }
#pragma unroll
      for (int mt = 0; mt < 4; mt++)
#pragma unroll
        for (int nt = 0; nt < 4; nt++)
          acc[mt][nt] = __builtin_amdgcn_mfma_f32_16x16x32_bf16(af[mt], bf[nt], acc[mt][nt], 0, 0, 0);
    }
  }

  if (MODE == 0 && sel == 2) {
    // V: transpose through LDS, write bf16 (B,1024,2048) directly.
    __syncthreads();  // all K-loop LDS reads finished before overwrite
#pragma unroll
    for (int mt = 0; mt < 4; mt++) {
      int r0 = wm * 64 + mt * 16 + quad * 4;
#pragma unroll
      for (int nt = 0; nt < 4; nt++) {
        int c = wn * 64 + nt * 16 + l16;
        float bvv = bias[bnl * 128 + c];
        u16x4 pk;
#pragma unroll
        for (int r = 0; r < 4; r++) pk[r] = f2bf(acc[mt][nt][r] + bvv);
        *(u16x4*)(smem + c * 132 + r0) = pk;
      }
    }
    __syncthreads();
    const int bb = bm >> 4;
    const size_t sb = (size_t)(bm & 15) * 128;
    u16* Cv = (u16*)C;
#pragma unroll
    for (int i = 0; i < 16; i++) {
      int idx = tid + i * 256;
      int dr = idx >> 5, c4 = (idx & 31) * 4;
      u16x4 v = *(const u16x4*)(smem + dr * 132 + c4);
      *(u16x4*)(Cv + ((size_t)bb * 1024 + bnl * 128 + dr) * 2048 + sb + c4) = v;
    }
  } else {
    const float cmul = (MODE == 0 && sel == 0) ? 0.125f : 1.0f;
#pragma unroll
    for (int mt = 0; mt < 4; mt++) {
      int row0 = bm * 128 + wm * 64 + mt * 16 + quad * 4;
#pragma unroll
      for (int nt = 0; nt < 4; nt++) {
        int col = bnl * 128 + wn * 64 + nt * 16 + l16;
        float bv = bias[col];
#pragma unroll
        for (int r = 0; r < 4; r++) {
          float v = (acc[mt][nt][r] + bv) * cmul;
          if (MODE) ((float*)C)[(size_t)(row0 + r) * 1024 + col] = v;
          else      ((u16*)C)[(size_t)(row0 + r) * 1024 + col] = f2bf(v);
        }
      }
    }
  }
}

// ---------------- fused causal attention ----------------
// v4 = v2 (256 threads, 4 waves, Q in regs, K dbuf w/ prefetch, hoisted
// rowsum, diag-only masking, setprio) + XCD-locality block remap ONLY.
// Remap: xcd = flat&7 (HW round-robin), slot = flat>>3. Each XCD owns 4
// (b,h) groups -> K+V working set 2MB fits its 4MB L2. Blocks flat and
// flat+256 share a CU with qb summing to 15 (load balance preserved).
__global__ __launch_bounds__(256) void attn_kernel(
    const u16* __restrict__ Qb, const u16* __restrict__ Kbuf,
    const u16* __restrict__ Vtb, float* __restrict__ attn,
    u16* __restrict__ ctx)
{
  __shared__ u16 Ks[2][128 * 64];  // sweep1: K dbuf; sweep2: [0]=K, [1]=Vt
  __shared__ u16 Ps[128 * 128];
  __shared__ float ls[128];

  const int flat = blockIdx.x;
  const int x = flat & 7, slot = flat >> 3;
  int bh, qb;
  if (slot < 32) { bh = x * 4 + (slot >> 4);            qb = slot & 15; }
  else           { bh = x * 4 + 2 + ((slot - 32) >> 4); qb = 15 - ((slot - 32) & 15); }
  const int b = bh >> 4, h = bh & 15;

  const int tid = threadIdx.x;
  const int w = tid >> 6, lane = tid & 63, quad = lane >> 4, l16 = lane & 15;
  const int wm = w >> 1, wn = w & 1;
  const int srow8 = lane >> 3, gc8 = (lane & 7) ^ srow8;
  const int srow16 = lane >> 4, sc16 = lane & 15;

  const int S = 2048, D = 1024;
  const u16* Qg = Qb + ((size_t)b * S + qb * 128) * D + h * 64;
  const u16* Kg = Kbuf + (size_t)b * S * D + h * 64;
  const u16* Vg = Vtb + ((size_t)b * D + h * 64) * S;
  float* attng = attn + ((size_t)(b * 16 + h) * S + qb * 128) * S;

  const f32x4 z4 = {0.f, 0.f, 0.f, 0.f};

  // stage Q -> Ps[0:8192) and K(0) -> Ks[0]; one barrier drains both
#pragma unroll
  for (int j = 0; j < 4; j++)
    glds16(Qg + (size_t)(w * 32 + j * 8 + srow8) * D + gc8 * 8, (u16*)Ps + (w * 4 + j) * 512);
  if (tid < 128) ls[tid] = 0.f;
#pragma unroll
  for (int j = 0; j < 4; j++)
    glds16(Kg + (size_t)(w * 32 + j * 8 + srow8) * D + gc8 * 8, Ks[0] + (w * 4 + j) * 512);
  __syncthreads();

  // Q fragments -> registers (invariant across kb loop)
  short8 qf[4][2];
#pragma unroll
  for (int mt = 0; mt < 4; mt++) {
    int row = wm * 64 + mt * 16 + l16;
#pragma unroll
    for (int ks = 0; ks < 2; ks++) {
      int chk = (ks * 4 + quad) ^ (row & 7);
      qf[mt][ks] = *(const short8*)((const short*)Ps + row * 64 + chk * 8);
    }
  }

  // ---- sweep 1: row sums of exp ----
  float rowsum[4][4];
#pragma unroll
  for (int mt = 0; mt < 4; mt++)
#pragma unroll
    for (int rr = 0; rr < 4; rr++) rowsum[mt][rr] = 0.f;

  for (int kb = 0; kb <= qb; kb++) {
    if (kb) __syncthreads();  // K(kb) ready (pre-loop barrier covers kb==0)
    if (kb < qb) {            // prefetch next tile; drained at NEXT top barrier
#pragma unroll
      for (int j = 0; j < 4; j++)
        glds16(Kg + (size_t)((kb + 1) * 128 + w * 32 + j * 8 + srow8) * D + gc8 * 8,
               Ks[(kb + 1) & 1] + (w * 4 + j) * 512);
    }
    const u16* kbf = Ks[kb & 1];
    f32x4 acc[4][4];
#pragma unroll
    for (int mt = 0; mt < 4; mt++)
#pragma unroll
      for (int nt = 0; nt < 4; nt++) acc[mt][nt] = z4;
    __builtin_amdgcn_s_setprio(1);
#pragma unroll
    for (int ks = 0; ks < 2; ks++) {
      short8 bf[4];
#pragma unroll
      for (int nt = 0; nt < 4; nt++) {
        int row = wn * 64 + nt * 16 + l16;
        int chk = (ks * 4 + quad) ^ (row & 7);
        bf[nt] = *(const short8*)((const short*)kbf + row * 64 + chk * 8);
      }
#pragma unroll
      for (int mt = 0; mt < 4; mt++)
#pragma unroll
        for (int nt = 0; nt < 4; nt++)
          acc[mt][nt] = __builtin_amdgcn_mfma_f32_16x16x32_bf16(qf[mt][ks], bf[nt], acc[mt][nt], 0, 0, 0);
    }
    __builtin_amdgcn_s_setprio(0);
    if (kb < qb) {  // full tile: no mask
#pragma unroll
      for (int mt = 0; mt < 4; mt++)
#pragma unroll
        for (int rr = 0; rr < 4; rr++) {
          float s = 0.f;
#pragma unroll
          for (int nt = 0; nt < 4; nt++)
            s += __expf(fminf(acc[mt][nt][rr], 30.f));
          rowsum[mt][rr] += s;
        }
    } else {        // diagonal tile: mask k>q
#pragma unroll
      for (int mt = 0; mt < 4; mt++)
#pragma unroll
        for (int rr = 0; rr < 4; rr++) {
          int rloc = wm * 64 + mt * 16 + quad * 4 + rr;
          float s = 0.f;
#pragma unroll
          for (int nt = 0; nt < 4; nt++) {
            int ck = wn * 64 + nt * 16 + l16;
            s += (ck <= rloc) ? __expf(fminf(acc[mt][nt][rr], 30.f)) : 0.f;
          }
          rowsum[mt][rr] += s;
        }
    }
  }

  // one reduction for the whole sweep
#pragma unroll
  for (int mt = 0; mt < 4; mt++)
#pragma unroll
    for (int rr = 0; rr < 4; rr++) {
      float s = rowsum[mt][rr];
      s += __shfl_xor(s, 1);
      s += __shfl_xor(s, 2);
      s += __shfl_xor(s, 4);
      s += __shfl_xor(s, 8);
      if (l16 == 0) atomicAdd(&ls[wm * 64 + mt * 16 + quad * 4 + rr], s);
    }
  __syncthreads();
  float rl[4][4];
#pragma unroll
  for (int mt = 0; mt < 4; mt++)
#pragma unroll
    for (int rr = 0; rr < 4; rr++)
      rl[mt][rr] = 1.0f / ls[wm * 64 + mt * 16 + quad * 4 + rr];

  // restage K(0) for sweep 2 (drained at first top barrier)
#pragma unroll
  for (int j = 0; j < 4; j++)
    glds16(Kg + (size_t)(w * 32 + j * 8 + srow8) * D + gc8 * 8, Ks[0] + (w * 4 + j) * 512);

  f32x4 cacc[2][4];
#pragma unroll
  for (int mt = 0; mt < 2; mt++)
#pragma unroll
    for (int nt = 0; nt < 4; nt++) cacc[mt][nt] = z4;

  // ---- sweep 2: attn values + PV ----
  for (int kb = 0; kb <= qb; kb++) {
    __syncthreads();  // K(kb) ready; prev PV reads + prev attn stores done
    // stage Vt(kb) -> Ks[1]; drained at mid barrier (covered by QK+exp)
#pragma unroll
    for (int j = 0; j < 4; j++) {
      int r0v = (w * 4 + j) * 4;
      int row = r0v + srow16;
      int gcv = sc16 ^ (row & 7);
      glds16(Vg + (size_t)row * S + kb * 128 + gcv * 8, Ks[1] + r0v * 128);
    }
    f32x4 acc[4][4];
#pragma unroll
    for (int mt = 0; mt < 4; mt++)
#pragma unroll
      for (int nt = 0; nt < 4; nt++) acc[mt][nt] = z4;
    __builtin_amdgcn_s_setprio(1);
#pragma unroll
    for (int ks = 0; ks < 2; ks++) {
      short8 bf[4];
#pragma unroll
      for (int nt = 0; nt < 4; nt++) {
        int row = wn * 64 + nt * 16 + l16;
        int chk = (ks * 4 + quad) ^ (row & 7);
        bf[nt] = *(const short8*)((const short*)Ks[0] + row * 64 + chk * 8);
      }
#pragma unroll
      for (int mt = 0; mt < 4; mt++)
#pragma unroll
        for (int nt = 0; nt < 4; nt++)
          acc[mt][nt] = __builtin_amdgcn_mfma_f32_16x16x32_bf16(qf[mt][ks], bf[nt], acc[mt][nt], 0, 0, 0);
    }
    __builtin_amdgcn_s_setprio(0);
    // epilogue: P -> Ps (bf16, XOR-swizzled rows), normalized
    bool diag = (kb == qb);
#pragma unroll
    for (int mt = 0; mt < 4; mt++)
#pragma unroll
      for (int rr = 0; rr < 4; rr++) {
        int rloc = wm * 64 + mt * 16 + quad * 4 + rr;
        float rlv = rl[mt][rr];
#pragma unroll
        for (int nt = 0; nt < 4; nt++) {
          int colk = wn * 64 + nt * 16 + l16;
          float e = __expf(fminf(acc[mt][nt][rr], 30.f)) * rlv;
          if (diag && colk > rloc) e = 0.f;
          Ps[rloc * 128 + (((colk >> 3) ^ (rloc & 7)) << 3) + (colk & 7)] = f2bf(e);
        }
      }
    __syncthreads();  // Ps ready + Vt drained
    // restage K(kb+1) (QK reads of Ks[0] all done); drained at next top barrier
    if (kb < qb) {
#pragma unroll
      for (int j = 0; j < 4; j++)
        glds16(Kg + (size_t)((kb + 1) * 128 + w * 32 + j * 8 + srow8) * D + gc8 * 8,
               Ks[0] + (w * 4 + j) * 512);
    }
    // attn write from Ps: coalesced NT dwordx4 (overlaps K prefetch latency)
#pragma unroll
    for (int s = 0; s < 16; s++) {
      int e4 = s * 256 + tid;
      int row = e4 >> 5, col = (e4 & 31) * 4;
      int chunk = (col >> 3) ^ (row & 7);
      u16x4 pv = *(const u16x4*)((const u16*)Ps + row * 128 + chunk * 8 + (col & 7));
      f32x4 o;
      o[0] = bf2f(pv[0]); o[1] = bf2f(pv[1]); o[2] = bf2f(pv[2]); o[3] = bf2f(pv[3]);
      __builtin_nontemporal_store(o, (f32x4*)(attng + (size_t)row * S + kb * 128 + col));
    }
    // PV: each wave 32 rows x 64 cols
    __builtin_amdgcn_s_setprio(1);
#pragma unroll
    for (int ks = 0; ks < 4; ks++) {
      short8 pf[2], vf[4];
#pragma unroll
      for (int mt = 0; mt < 2; mt++) {
        int row = w * 32 + mt * 16 + l16;
        int chk = (ks * 4 + quad) ^ (row & 7);
        pf[mt] = *(const short8*)((const short*)Ps + row * 128 + chk * 8);
      }
#pragma unroll
      for (int nt = 0; nt < 4; nt++) {
        int row = nt * 16 + l16;
        int chk = (ks * 4 + quad) ^ (row & 7);
        vf[nt] = *(const short8*)((const short*)Ks[1] + row * 128 + chk * 8);
      }
#pragma unroll
      for (int mt = 0; mt < 2; mt++)
#pragma unroll
        for (int nt = 0; nt < 4; nt++)
          cacc[mt][nt] = __builtin_amdgcn_mfma_f32_16x16x32_bf16(pf[mt], vf[nt], cacc[mt][nt], 0, 0, 0);
    }
    __builtin_amdgcn_s_setprio(0);
  }

  // zero-fill strictly-upper k-blocks of attn (NT)
  {
    int kstart = (qb + 1) * 128;
    const f32x4 zz = {0.f, 0.f, 0.f, 0.f};
    for (int rr = 0; rr < 128; rr++) {
      float* rowp = attng + (size_t)rr * S;
      for (int c = kstart + tid * 4; c < S; c += 1024)
        __builtin_nontemporal_store(zz, (f32x4*)(rowp + c));
    }
  }

  // ctx write (bf16, (B,S,D) layout)
#pragma unroll
  for (int mt = 0; mt < 2; mt++)
#pragma unroll
    for (int nt = 0; nt < 4; nt++)
#pragma unroll
      for (int rr = 0; rr < 4; rr++) {
        int row_local = w * 32 + mt * 16 + quad * 4 + rr;
        int col = nt * 16 + l16;
        ctx[((size_t)b * S + qb * 128 + row_local) * D + h * 64 + col] = f2bf(cacc[mt][nt][rr]);
      }
}

extern "C" void kernel_launch(void* const* d_in, const int* in_sizes, int n_in,
                              void* d_out, int out_size, void* d_ws, size_t ws_size,
                              hipStream_t stream) {
  const float* x  = (const float*)d_in[0];
  const float* Wq = (const float*)d_in[1];
  const float* bq = (const float*)d_in[2];
  const float* Wk = (const float*)d_in[3];
  const float* bk = (const float*)d_in[4];
  const float* Wv = (const float*)d_in[5];
  const float* bv = (const float*)d_in[6];
  const float* Wo = (const float*)d_in[7];
  const float* bo = (const float*)d_in[8];

  float* out_f32  = (float*)d_out;              // (B,S,D) fp32
  float* attn_out = (float*)d_out + 4194304;    // (B,H,S,S) fp32

  char* w = (char*)d_ws;
  u16* xb   = (u16*)(w + 0);
  u16* Wqb  = (u16*)(w + 8388608);
  u16* Wkb  = (u16*)(w + 10485760);
  u16* Wvb  = (u16*)(w + 12582912);
  u16* Wob  = (u16*)(w + 14680064);
  u16* Qbuf = (u16*)(w + 16777216);
  u16* Kbuf = (u16*)(w + 25165824);
  u16* Vtb  = (u16*)(w + 41943040);
  u16* ctxb = (u16*)(w + 50331648);

  cast_all<<<8192, 256, 0, stream>>>(x, Wq, Wk, Wv, Wo, xb, Wqb, Wkb, Wvb, Wob);

  // fused QKV projection; Q pre-scaled by 0.125; V written transposed
  gemm_nt_glds<0><<<dim3(24, 32), 256, 0, stream>>>(
      xb, Wqb, Wkb, Wvb, bq, bk, bv, Qbuf, Kbuf, Vtb, 1024);

  attn_kernel<<<512, 256, 0, stream>>>(Qbuf, Kbuf, Vtb, attn_out, ctxb);

  gemm_nt_glds<1><<<dim3(8, 32), 256, 0, stream>>>(
      ctxb, Wob, Wob, Wob, bo, bo, bo, out_f32, out_f32, out_f32, 1024);
}

// Round 6
// 685.785 us; speedup vs baseline: 1.1309x; 1.0089x over previous
//
#include <hip/hip_runtime.h>

typedef unsigned short u16;
using short8 = __attribute__((ext_vector_type(8))) short;
using f32x4  = __attribute__((ext_vector_type(4))) float;
using u16x4  = __attribute__((ext_vector_type(4))) unsigned short;

__device__ __forceinline__ u16 f2bf(float f) {
  union { float f; unsigned int u; } v; v.f = f;
  unsigned int u = v.u + 0x7FFFu + ((v.u >> 16) & 1u);
  return (u16)(u >> 16);
}
__device__ __forceinline__ float bf2f(u16 u) {
  union { unsigned int u; float f; } v; v.u = ((unsigned int)u) << 16;
  return v.f;
}
// async global->LDS, 16B per lane. LDS dest = wave-uniform base + lane*16.
__device__ __forceinline__ void glds16(const void* g, void* l) {
  __builtin_amdgcn_global_load_lds(
      (const __attribute__((address_space(1))) void*)g,
      (__attribute__((address_space(3))) void*)l, 16, 0, 0);
}

// ---------------- merged f32 -> bf16 casts ----------------
__global__ __launch_bounds__(256) void cast_all(
    const float* __restrict__ x, const float* __restrict__ wq,
    const float* __restrict__ wk, const float* __restrict__ wv,
    const float* __restrict__ wo,
    u16* __restrict__ xb, u16* __restrict__ wqb, u16* __restrict__ wkb,
    u16* __restrict__ wvb, u16* __restrict__ wob) {
  int i = blockIdx.x * 256 + threadIdx.x;
  const float4* src; ushort4* dst; int off;
  if (i < 1048576)      { src = (const float4*)x;  dst = (ushort4*)xb;  off = i; }
  else if (i < 1310720) { src = (const float4*)wq; dst = (ushort4*)wqb; off = i - 1048576; }
  else if (i < 1572864) { src = (const float4*)wk; dst = (ushort4*)wkb; off = i - 1310720; }
  else if (i < 1835008) { src = (const float4*)wv; dst = (ushort4*)wvb; off = i - 1572864; }
  else                  { src = (const float4*)wo; dst = (ushort4*)wob; off = i - 1835008; }
  float4 v = src[off];
  ushort4 o;
  o.x = f2bf(v.x); o.y = f2bf(v.y); o.z = f2bf(v.z); o.w = f2bf(v.w);
  dst[off] = o;
}

// ---------------- NT GEMM with global_load_lds staging ----------------
// MODE 0: fused QKV. sel0 -> Q bf16 scaled by 0.125 (exact pow2, folded attn scale);
//         sel1 -> K bf16; sel2 -> V written TRANSPOSED bf16 into (B,1024,2048).
// MODE 1: fp32 out (output projection).
template<int MODE>
__global__ __launch_bounds__(256) void gemm_nt_glds(
    const u16* __restrict__ A,
    const u16* __restrict__ B0, const u16* __restrict__ B1, const u16* __restrict__ B2,
    const float* __restrict__ bias0, const float* __restrict__ bias1, const float* __restrict__ bias2,
    void* __restrict__ C0, void* __restrict__ C1, void* __restrict__ C2,
    int K)
{
  // As = smem[0:8192) u16, Bs = smem[8192:16384); full array doubles as 128x132
  // transpose scratch for the sel==2 epilogue (pad 132 -> conflict-free, 8B aligned).
  __shared__ u16 smem[16896];
  u16* As = smem;
  u16* Bs = smem + 8192;
  const int bn = blockIdx.x, bm = blockIdx.y;
  const int sel = bn >> 3, bnl = bn & 7;
  const u16* B = sel == 0 ? B0 : (sel == 1 ? B1 : B2);
  const float* bias = sel == 0 ? bias0 : (sel == 1 ? bias1 : bias2);
  void* C = sel == 0 ? C0 : (sel == 1 ? C1 : C2);

  const int tid = threadIdx.x;
  const int w = tid >> 6, lane = tid & 63, quad = lane >> 4, l16 = lane & 15;
  const int wm = w >> 1, wn = w & 1;
  const int srow = lane >> 3, gc = (lane & 7) ^ srow;

  const u16* aseg = A + (size_t)(bm * 128 + w * 32 + srow) * K + gc * 8;
  const u16* bseg = B + (size_t)(bnl * 128 + w * 32 + srow) * K + gc * 8;

  const f32x4 z4 = {0.f, 0.f, 0.f, 0.f};
  f32x4 acc[4][4];
#pragma unroll
  for (int mt = 0; mt < 4; mt++)
#pragma unroll
    for (int nt = 0; nt < 4; nt++) acc[mt][nt] = z4;

  for (int k0 = 0; k0 < K; k0 += 64) {
    __syncthreads();
#pragma unroll
    for (int j = 0; j < 4; j++) {
      glds16(aseg + (size_t)(j * 8) * K + k0, As + (w * 4 + j) * 512);
      glds16(bseg + (size_t)(j * 8) * K + k0, Bs + (w * 4 + j) * 512);
    }
    __syncthreads();
#pragma unroll
    for (int ks = 0; ks < 2; ks++) {
      short8 af[4], bf[4];
#pragma unroll
      for (int mt = 0; mt < 4; mt++) {
        int row = wm * 64 + mt * 16 + l16;
        int chk = (ks * 4 + quad) ^ (row & 7);
        af[mt] = *(const short8*)((const short*)As + row * 64 + chk * 8);
      }
#pragma unroll
      for (int nt = 0; nt < 4; nt++) {
        int row = wn * 64 + nt * 16 + l16;
        int chk = (ks * 4 + quad) ^ (row & 7);
        bf[nt] = *(const short8*)((const short*)Bs + row * 64 + chk * 8);
      }
#pragma unroll
      for (int mt = 0; mt < 4; mt++)
#pragma unroll
        for (int nt = 0; nt < 4; nt++)
          acc[mt][nt] = __builtin_amdgcn_mfma_f32_16x16x32_bf16(af[mt], bf[nt], acc[mt][nt], 0, 0, 0);
    }
  }

  if (MODE == 0 && sel == 2) {
    // V: transpose through LDS, write bf16 (B,1024,2048) directly.
    __syncthreads();  // all K-loop LDS reads finished before overwrite
#pragma unroll
    for (int mt = 0; mt < 4; mt++) {
      int r0 = wm * 64 + mt * 16 + quad * 4;
#pragma unroll
      for (int nt = 0; nt < 4; nt++) {
        int c = wn * 64 + nt * 16 + l16;
        float bvv = bias[bnl * 128 + c];
        u16x4 pk;
#pragma unroll
        for (int r = 0; r < 4; r++) pk[r] = f2bf(acc[mt][nt][r] + bvv);
        *(u16x4*)(smem + c * 132 + r0) = pk;
      }
    }
    __syncthreads();
    const int bb = bm >> 4;
    const size_t sb = (size_t)(bm & 15) * 128;
    u16* Cv = (u16*)C;
#pragma unroll
    for (int i = 0; i < 16; i++) {
      int idx = tid + i * 256;
      int dr = idx >> 5, c4 = (idx & 31) * 4;
      u16x4 v = *(const u16x4*)(smem + dr * 132 + c4);
      *(u16x4*)(Cv + ((size_t)bb * 1024 + bnl * 128 + dr) * 2048 + sb + c4) = v;
    }
  } else {
    const float cmul = (MODE == 0 && sel == 0) ? 0.125f : 1.0f;
#pragma unroll
    for (int mt = 0; mt < 4; mt++) {
      int row0 = bm * 128 + wm * 64 + mt * 16 + quad * 4;
#pragma unroll
      for (int nt = 0; nt < 4; nt++) {
        int col = bnl * 128 + wn * 64 + nt * 16 + l16;
        float bv = bias[col];
#pragma unroll
        for (int r = 0; r < 4; r++) {
          float v = (acc[mt][nt][r] + bv) * cmul;
          if (MODE) ((float*)C)[(size_t)(row0 + r) * 1024 + col] = v;
          else      ((u16*)C)[(size_t)(row0 + r) * 1024 + col] = f2bf(v);
        }
      }
    }
  }
}

// ---------------- fused causal attention ----------------
// v5 = v4 + swapped QK^T operands (acc: k=row, q=col) so the P-epilogue
// packs 4 consecutive k into one ds_write_b64 (was 64x ds_write_b16);
// rowsum/rl are 4 regs (q lane-fixed); counted vmcnt(16) top barrier in
// sweep 2 keeps attn stores in flight across the barrier.
__global__ __launch_bounds__(256) void attn_kernel(
    const u16* __restrict__ Qb, const u16* __restrict__ Kbuf,
    const u16* __restrict__ Vtb, float* __restrict__ attn,
    u16* __restrict__ ctx)
{
  __shared__ u16 Ks[2][128 * 64];  // sweep1: K dbuf; sweep2: [0]=K, [1]=Vt
  __shared__ u16 Ps[128 * 128];
  __shared__ float ls[128];

  // XCD-locality remap (verified -22us): xcd = flat&7, slot = flat>>3.
  const int flat = blockIdx.x;
  const int x = flat & 7, slot = flat >> 3;
  int bh, qb;
  if (slot < 32) { bh = x * 4 + (slot >> 4);            qb = slot & 15; }
  else           { bh = x * 4 + 2 + ((slot - 32) >> 4); qb = 15 - ((slot - 32) & 15); }
  const int b = bh >> 4, h = bh & 15;

  const int tid = threadIdx.x;
  const int w = tid >> 6, lane = tid & 63, quad = lane >> 4, l16 = lane & 15;
  const int wm = w >> 1, wn = w & 1;
  const int srow8 = lane >> 3, gc8 = (lane & 7) ^ srow8;
  const int srow16 = lane >> 4, sc16 = lane & 15;

  const int S = 2048, D = 1024;
  const u16* Qg = Qb + ((size_t)b * S + qb * 128) * D + h * 64;
  const u16* Kg = Kbuf + (size_t)b * S * D + h * 64;
  const u16* Vg = Vtb + ((size_t)b * D + h * 64) * S;
  float* attng = attn + ((size_t)(b * 16 + h) * S + qb * 128) * S;

  const f32x4 z4 = {0.f, 0.f, 0.f, 0.f};

  // stage Q -> Ps[0:8192) and K(0) -> Ks[0]; one barrier drains both
#pragma unroll
  for (int j = 0; j < 4; j++)
    glds16(Qg + (size_t)(w * 32 + j * 8 + srow8) * D + gc8 * 8, (u16*)Ps + (w * 4 + j) * 512);
  if (tid < 128) ls[tid] = 0.f;
#pragma unroll
  for (int j = 0; j < 4; j++)
    glds16(Kg + (size_t)(w * 32 + j * 8 + srow8) * D + gc8 * 8, Ks[0] + (w * 4 + j) * 512);
  __syncthreads();

  // Q fragments -> registers; q-row = wn*64 + nt*16 + l16 (B-operand in both sweeps)
  short8 qf[4][2];
#pragma unroll
  for (int nt = 0; nt < 4; nt++) {
    int row = wn * 64 + nt * 16 + l16;
#pragma unroll
    for (int ks = 0; ks < 2; ks++) {
      int chk = (ks * 4 + quad) ^ (row & 7);
      qf[nt][ks] = *(const short8*)((const short*)Ps + row * 64 + chk * 8);
    }
  }

  // ---- sweep 1: row sums of exp (acc: k=row(quad*4+rr via mt), q=col(l16 via nt)) ----
  float rowsum[4];
#pragma unroll
  for (int nt = 0; nt < 4; nt++) rowsum[nt] = 0.f;

  for (int kb = 0; kb <= qb; kb++) {
    if (kb) __syncthreads();  // K(kb) ready (pre-loop barrier covers kb==0)
    if (kb < qb) {            // prefetch next tile; drained at NEXT top barrier
#pragma unroll
      for (int j = 0; j < 4; j++)
        glds16(Kg + (size_t)((kb + 1) * 128 + w * 32 + j * 8 + srow8) * D + gc8 * 8,
               Ks[(kb + 1) & 1] + (w * 4 + j) * 512);
    }
    const u16* kbf = Ks[kb & 1];
    f32x4 acc[4][4];
#pragma unroll
    for (int mt = 0; mt < 4; mt++)
#pragma unroll
      for (int nt = 0; nt < 4; nt++) acc[mt][nt] = z4;
    __builtin_amdgcn_s_setprio(1);
#pragma unroll
    for (int ks = 0; ks < 2; ks++) {
      short8 af[4];
#pragma unroll
      for (int mt = 0; mt < 4; mt++) {
        int row = wm * 64 + mt * 16 + l16;
        int chk = (ks * 4 + quad) ^ (row & 7);
        af[mt] = *(const short8*)((const short*)kbf + row * 64 + chk * 8);
      }
#pragma unroll
      for (int mt = 0; mt < 4; mt++)
#pragma unroll
        for (int nt = 0; nt < 4; nt++)
          acc[mt][nt] = __builtin_amdgcn_mfma_f32_16x16x32_bf16(af[mt], qf[nt][ks], acc[mt][nt], 0, 0, 0);
    }
    __builtin_amdgcn_s_setprio(0);
    if (kb < qb) {  // full tile: no mask
#pragma unroll
      for (int nt = 0; nt < 4; nt++) {
        float s = 0.f;
#pragma unroll
        for (int mt = 0; mt < 4; mt++)
#pragma unroll
          for (int rr = 0; rr < 4; rr++)
            s += __expf(fminf(acc[mt][nt][rr], 30.f));
        rowsum[nt] += s;
      }
    } else {        // diagonal tile: mask k>q
#pragma unroll
      for (int nt = 0; nt < 4; nt++) {
        int q = wn * 64 + nt * 16 + l16;
        float s = 0.f;
#pragma unroll
        for (int mt = 0; mt < 4; mt++)
#pragma unroll
          for (int rr = 0; rr < 4; rr++) {
            int k = wm * 64 + mt * 16 + quad * 4 + rr;
            s += (k <= q) ? __expf(fminf(acc[mt][nt][rr], 30.f)) : 0.f;
          }
        rowsum[nt] += s;
      }
    }
  }

  // one reduction for the whole sweep: combine quads, then across wm-waves via atomic
#pragma unroll
  for (int nt = 0; nt < 4; nt++) {
    float s = rowsum[nt];
    s += __shfl_xor(s, 16);
    s += __shfl_xor(s, 32);
    if (quad == 0) atomicAdd(&ls[wn * 64 + nt * 16 + l16], s);
  }
  __syncthreads();
  float rl[4];
#pragma unroll
  for (int nt = 0; nt < 4; nt++)
    rl[nt] = 1.0f / ls[wn * 64 + nt * 16 + l16];

  // restage K(0) for sweep 2 (drained at first top barrier)
#pragma unroll
  for (int j = 0; j < 4; j++)
    glds16(Kg + (size_t)(w * 32 + j * 8 + srow8) * D + gc8 * 8, Ks[0] + (w * 4 + j) * 512);

  f32x4 cacc[2][4];
#pragma unroll
  for (int mt = 0; mt < 2; mt++)
#pragma unroll
    for (int nt = 0; nt < 4; nt++) cacc[mt][nt] = z4;

  // ---- sweep 2: attn values + PV ----
  for (int kb = 0; kb <= qb; kb++) {
    if (kb == 0) {
      __syncthreads();  // K(0) ready (full drain)
    } else {
      // counted barrier: 4 K-glds are older than the 16 attn stores ->
      // vmcnt(16) guarantees K(kb) in LDS while stores stay in flight.
      asm volatile("s_waitcnt vmcnt(16)" ::: "memory");
      __builtin_amdgcn_s_barrier();
      __builtin_amdgcn_sched_barrier(0);
    }
    // stage Vt(kb) -> Ks[1]; drained at mid barrier (covered by QK+exp)
#pragma unroll
    for (int j = 0; j < 4; j++) {
      int r0v = (w * 4 + j) * 4;
      int row = r0v + srow16;
      int gcv = sc16 ^ (row & 7);
      glds16(Vg + (size_t)row * S + kb * 128 + gcv * 8, Ks[1] + r0v * 128);
    }
    f32x4 acc[4][4];
#pragma unroll
    for (int mt = 0; mt < 4; mt++)
#pragma unroll
      for (int nt = 0; nt < 4; nt++) acc[mt][nt] = z4;
    __builtin_amdgcn_s_setprio(1);
#pragma unroll
    for (int ks = 0; ks < 2; ks++) {
      short8 af[4];
#pragma unroll
      for (int mt = 0; mt < 4; mt++) {
        int row = wm * 64 + mt * 16 + l16;
        int chk = (ks * 4 + quad) ^ (row & 7);
        af[mt] = *(const short8*)((const short*)Ks[0] + row * 64 + chk * 8);
      }
#pragma unroll
      for (int mt = 0; mt < 4; mt++)
#pragma unroll
        for (int nt = 0; nt < 4; nt++)
          acc[mt][nt] = __builtin_amdgcn_mfma_f32_16x16x32_bf16(af[mt], qf[nt][ks], acc[mt][nt], 0, 0, 0);
    }
    __builtin_amdgcn_s_setprio(0);
    // epilogue: P -> Ps, vectorized b64 (4 consecutive k per register quad)
    bool diag = (kb == qb);
#pragma unroll
    for (int mt = 0; mt < 4; mt++) {
      int kbase = wm * 64 + mt * 16 + quad * 4;
#pragma unroll
      for (int nt = 0; nt < 4; nt++) {
        int q = wn * 64 + nt * 16 + l16;
        float rlv = rl[nt];
        u16x4 pk;
#pragma unroll
        for (int rr = 0; rr < 4; rr++) {
          float e = __expf(fminf(acc[mt][nt][rr], 30.f)) * rlv;
          if (diag && (kbase + rr) > q) e = 0.f;
          pk[rr] = f2bf(e);
        }
        *(u16x4*)((u16*)Ps + q * 128 + (((kbase >> 3) ^ (q & 7)) << 3) + (kbase & 7)) = pk;
      }
    }
    __syncthreads();  // Ps ready + Vt drained
    // restage K(kb+1) (QK reads of Ks[0] all done); drained at next top barrier
    if (kb < qb) {
#pragma unroll
      for (int j = 0; j < 4; j++)
        glds16(Kg + (size_t)((kb + 1) * 128 + w * 32 + j * 8 + srow8) * D + gc8 * 8,
               Ks[0] + (w * 4 + j) * 512);
    }
    // attn write from Ps: coalesced NT dwordx4 (overlaps K prefetch latency)
#pragma unroll
    for (int s = 0; s < 16; s++) {
      int e4 = s * 256 + tid;
      int row = e4 >> 5, col = (e4 & 31) * 4;
      int chunk = (col >> 3) ^ (row & 7);
      u16x4 pv = *(const u16x4*)((const u16*)Ps + row * 128 + chunk * 8 + (col & 7));
      f32x4 o;
      o[0] = bf2f(pv[0]); o[1] = bf2f(pv[1]); o[2] = bf2f(pv[2]); o[3] = bf2f(pv[3]);
      __builtin_nontemporal_store(o, (f32x4*)(attng + (size_t)row * S + kb * 128 + col));
    }
    // PV: each wave 32 rows x 64 cols
    __builtin_amdgcn_s_setprio(1);
#pragma unroll
    for (int ks = 0; ks < 4; ks++) {
      short8 pf[2], vf[4];
#pragma unroll
      for (int mt = 0; mt < 2; mt++) {
        int row = w * 32 + mt * 16 + l16;
        int chk = (ks * 4 + quad) ^ (row & 7);
        pf[mt] = *(const short8*)((const short*)Ps + row * 128 + chk * 8);
      }
#pragma unroll
      for (int nt = 0; nt < 4; nt++) {
        int row = nt * 16 + l16;
        int chk = (ks * 4 + quad) ^ (row & 7);
        vf[nt] = *(const short8*)((const short*)Ks[1] + row * 128 + chk * 8);
      }
#pragma unroll
      for (int mt = 0; mt < 2; mt++)
#pragma unroll
        for (int nt = 0; nt < 4; nt++)
          cacc[mt][nt] = __builtin_amdgcn_mfma_f32_16x16x32_bf16(pf[mt], vf[nt], cacc[mt][nt], 0, 0, 0);
    }
    __builtin_amdgcn_s_setprio(0);
  }

  // zero-fill strictly-upper k-blocks of attn (NT)
  {
    int kstart = (qb + 1) * 128;
    const f32x4 zz = {0.f, 0.f, 0.f, 0.f};
    for (int rr = 0; rr < 128; rr++) {
      float* rowp = attng + (size_t)rr * S;
      for (int c = kstart + tid * 4; c < S; c += 1024)
        __builtin_nontemporal_store(zz, (f32x4*)(rowp + c));
    }
  }

  // ctx write (bf16, (B,S,D) layout)
#pragma unroll
  for (int mt = 0; mt < 2; mt++)
#pragma unroll
    for (int nt = 0; nt < 4; nt++)
#pragma unroll
      for (int rr = 0; rr < 4; rr++) {
        int row_local = w * 32 + mt * 16 + quad * 4 + rr;
        int col = nt * 16 + l16;
        ctx[((size_t)b * S + qb * 128 + row_local) * D + h * 64 + col] = f2bf(cacc[mt][nt][rr]);
      }
}

extern "C" void kernel_launch(void* const* d_in, const int* in_sizes, int n_in,
                              void* d_out, int out_size, void* d_ws, size_t ws_size,
                              hipStream_t stream) {
  const float* x  = (const float*)d_in[0];
  const float* Wq = (const float*)d_in[1];
  const float* bq = (const float*)d_in[2];
  const float* Wk = (const float*)d_in[3];
  const float* bk = (const float*)d_in[4];
  const float* Wv = (const float*)d_in[5];
  const float* bv = (const float*)d_in[6];
  const float* Wo = (const float*)d_in[7];
  const float* bo = (const float*)d_in[8];

  float* out_f32  = (float*)d_out;              // (B,S,D) fp32
  float* attn_out = (float*)d_out + 4194304;    // (B,H,S,S) fp32

  char* w = (char*)d_ws;
  u16* xb   = (u16*)(w + 0);
  u16* Wqb  = (u16*)(w + 8388608);
  u16* Wkb  = (u16*)(w + 10485760);
  u16* Wvb  = (u16*)(w + 12582912);
  u16* Wob  = (u16*)(w + 14680064);
  u16* Qbuf = (u16*)(w + 16777216);
  u16* Kbuf = (u16*)(w + 25165824);
  u16* Vtb  = (u16*)(w + 41943040);
  u16* ctxb = (u16*)(w + 50331648);

  cast_all<<<8192, 256, 0, stream>>>(x, Wq, Wk, Wv, Wo, xb, Wqb, Wkb, Wvb, Wob);

  // fused QKV projection; Q pre-scaled by 0.125; V written transposed
  gemm_nt_glds<0><<<dim3(24, 32), 256, 0, stream>>>(
      xb, Wqb, Wkb, Wvb, bq, bk, bv, Qbuf, Kbuf, Vtb, 1024);

  attn_kernel<<<512, 256, 0, stream>>>(Qbuf, Kbuf, Vtb, attn_out, ctxb);

  gemm_nt_glds<1><<<dim3(8, 32), 256, 0, stream>>>(
      ctxb, Wob, Wob, Wob, bo, bo, bo, out_f32, out_f32, out_f32, 1024);
}